// Round 3
// baseline (27318.704 us; speedup 1.0000x reference)
//
#include <hip/hip_runtime.h>
#include <hip/hip_cooperative_groups.h>
#include <math.h>

namespace cg = cooperative_groups;

#define NBLK 256
#define NTHR 512

// workspace offsets (floats)
#define OFF_XT   0          // XT[1600][64]: 0..63 y_hat^T, 64..575 ctx^T, 576..1087 hs ping, 1088..1599 hs pong
#define OFF_CS   102400     // cs^T [512][64]
#define OFF_E    135168     // e[64][1024]
#define OFF_PB   200704     // per-block maxes [256]
#define OFF_LENS 200960     // int lens[64]
#define OFF_W2   201024     // W2[64][1024] = fc2w @ fc1w
#define OFF_B2   266560     // b2[64]
#define OFF_CP   266624     // ctx partials [64 b][4 tc][512 d]

// output offsets (floats)
#define OUT_YH   0          // [64][128][64]
#define OUT_LENS 524288     // [64]
#define OUT_ATT  524352     // [64][1][128][1024]

__device__ __forceinline__ float sigf(float x) { return 1.0f / (1.0f + __expf(-x)); }
__device__ __forceinline__ float dot4(float4 a, float4 b) {
    return a.x * b.x + a.y * b.y + a.z * b.z + a.w * b.w;
}

__global__ __launch_bounds__(NTHR, 1) void mega(
    const float* __restrict__ h, const float* __restrict__ Wih,
    const float* __restrict__ Whh, const float* __restrict__ bih,
    const float* __restrict__ bhh, const float* __restrict__ fc1w,
    const float* __restrict__ fc1b, const float* __restrict__ fc2w,
    const int* __restrict__ slen, float* ws, float* __restrict__ out)
{
    cg::grid_group grid = cg::this_grid();
    const int blk = blockIdx.x;
    const int tid = threadIdx.x;
    const int lane = tid & 63;
    const int w = tid >> 6;

    __shared__ float gpart[8][2][4][64];   // 16 KB (P1)
    __shared__ float red[512];             // 2 KB  (P3)
    __shared__ float a_sh[256];            // 1 KB  (P3)
    __shared__ float feat[1024];           // 4 KB  (P4)
    __shared__ float lg_s[64];
    __shared__ float smax[8];

    // ---------------- init ----------------
    if (blk < 200) {                        // XT[1600][64] = 102400 = 200*512
        int idx = blk * 512 + tid;
        int k = idx >> 6, b = idx & 63;
        float v = 0.0f;
        if (k == 0) v = 1.0f;                                   // one-hot SOS
        else if (k >= 64 && k < 576) v = h[(size_t)b * 524288 + (k - 64)];
        ws[OFF_XT + idx] = v;                                   // hs ping+pong rows -> 0
    }
    if (blk < 64) ws[OFF_CS + blk * 512 + tid] = 0.0f;
    if (blk >= 64 && blk < 128) {           // W2 = fc2w @ fc1w
        int v = blk - 64;
#pragma unroll
        for (int rep = 0; rep < 2; ++rep) {
            int k = tid + rep * 512;
            float a = 0.0f;
            for (int m = 0; m < 128; ++m) a += fc2w[v * 128 + m] * fc1w[(size_t)m * 1024 + k];
            ws[OFF_W2 + (size_t)v * 1024 + k] = a;
        }
        if (tid == 0) {
            float a = 0.0f;
            for (int m = 0; m < 128; ++m) a += fc2w[v * 128 + m] * fc1b[m];
            ws[OFF_B2 + v] = a;
        }
    }
    if (blk == 128 && tid < 64) ((int*)ws)[OFF_LENS + tid] = 128;
    grid.sync();

    for (int ts = 0; ts < 128; ++ts) {
        const int hs_in  = 576 + ((ts & 1) ? 512 : 0);
        const int hs_out = 576 + ((ts & 1) ? 0 : 512);

        // ---- P1: gates (full K, 8 rows/wave, K-eighth) + LSTM cell ----
        {
            const int u0 = blk * 2;
            const int kq = __builtin_amdgcn_readfirstlane(w);
            float acc[2][4] = {{0, 0, 0, 0}, {0, 0, 0, 0}};
            int k = kq * 136, k1 = k + 136;
            for (; k < k1 && k < 576; ++k) {
                float xv = ws[OFF_XT + k * 64 + lane];
#pragma unroll
                for (int uu = 0; uu < 2; ++uu)
#pragma unroll
                    for (int g = 0; g < 4; ++g)
                        acc[uu][g] += Wih[(size_t)(g * 512 + u0 + uu) * 576 + k] * xv;
            }
            for (; k < k1; ++k) {
                float xv = ws[OFF_XT + (hs_in + k - 576) * 64 + lane];
#pragma unroll
                for (int uu = 0; uu < 2; ++uu)
#pragma unroll
                    for (int g = 0; g < 4; ++g)
                        acc[uu][g] += Whh[(size_t)(g * 512 + u0 + uu) * 512 + (k - 576)] * xv;
            }
#pragma unroll
            for (int uu = 0; uu < 2; ++uu)
#pragma unroll
                for (int g = 0; g < 4; ++g)
                    gpart[w][uu][g][lane] = acc[uu][g];
            __syncthreads();
            if (tid < 128) {
                int uu = tid >> 6, b = tid & 63;
                int u = u0 + uu;
                float g4[4];
#pragma unroll
                for (int g = 0; g < 4; ++g) {
                    float s = 0.0f;
#pragma unroll
                    for (int ww = 0; ww < 8; ++ww) s += gpart[ww][uu][g][b];
                    g4[g] = s + bih[g * 512 + u] + bhh[g * 512 + u];
                }
                int idx = u * 64 + b;
                float co = ws[OFF_CS + idx];
                float I = sigf(g4[0]), F = sigf(g4[1]), G = tanhf(g4[2]), O = sigf(g4[3]);
                float cn = F * co + I * G;
                ws[OFF_CS + idx] = cn;
                ws[OFF_XT + (hs_out + u) * 64 + b] = O * tanhf(cn);
            }
        }
        grid.sync();

        // ---- P2: e scores (all t; global max needs them) + per-block max ----
        {
            const int b = blk >> 2, tc = blk & 3;
            float hsv[8];
#pragma unroll
            for (int j = 0; j < 8; ++j)
                hsv[j] = ws[OFF_XT + (size_t)(hs_out + lane * 8 + j) * 64 + b];
            const float4* h4 = (const float4*)(h + ((size_t)b * 1024 + tc * 256 + w * 32) * 512);
            float rmax = -INFINITY;
            for (int i = 0; i < 32; ++i) {
                float4 p = h4[(size_t)i * 128 + lane * 2];
                float4 q = h4[(size_t)i * 128 + lane * 2 + 1];
                float part = p.x * hsv[0] + p.y * hsv[1] + p.z * hsv[2] + p.w * hsv[3]
                           + q.x * hsv[4] + q.y * hsv[5] + q.z * hsv[6] + q.w * hsv[7];
#pragma unroll
                for (int mm = 1; mm < 64; mm <<= 1) part += __shfl_xor(part, mm);
                if (lane == 0) ws[OFF_E + (size_t)b * 1024 + tc * 256 + w * 32 + i] = part;
                rmax = fmaxf(rmax, part);
            }
            if (lane == 0) smax[w] = rmax;
            __syncthreads();
            if (tid == 0) {
                float m = smax[0];
#pragma unroll
                for (int j = 1; j < 8; ++j) m = fmaxf(m, smax[j]);
                ws[OFF_PB + blk] = m;
            }
        }
        grid.sync();

        // ---- P3: global max + masked softmax (+EPS) + att write + ctx partial ----
        {
            const int b = blk >> 2, tc = blk & 3;
            red[tid] = (tid < 256) ? ws[OFF_PB + tid] : -INFINITY;
            __syncthreads();
            for (int s = 256; s > 0; s >>= 1) {
                if (tid < s) red[tid] = fmaxf(red[tid], red[tid + s]);
                __syncthreads();
            }
            float m = red[0];
            __syncthreads();
            int L = slen[b];
            float loc = 0.0f;
#pragma unroll
            for (int qq = 0; qq < 2; ++qq) {
                int t = tid + qq * 512;
                float e = ws[OFF_E + (size_t)b * 1024 + t];
                loc += (t < L) ? __expf(e - m) : 0.0f;
            }
            red[tid] = loc;
            __syncthreads();
            for (int s = 256; s > 0; s >>= 1) {
                if (tid < s) red[tid] += red[tid + s];
                __syncthreads();
            }
            float inv = 1.0f / (red[0] + 1e-5f);
            if (tid < 256) {
                int t = tc * 256 + tid;
                float e = ws[OFF_E + (size_t)b * 1024 + t];
                float a = (t < L) ? __expf(e - m) * inv : 0.0f;
                a_sh[tid] = a;
                out[OUT_ATT + (size_t)b * 131072 + (size_t)ts * 1024 + t] = a;
            }
            __syncthreads();
            int tmax = L - tc * 256;
            if (tmax > 256) tmax = 256;
            float acc = 0.0f;
            const float* hb = h + ((size_t)b * 1024 + tc * 256) * 512 + tid;
#pragma unroll 4
            for (int i = 0; i < tmax; ++i) acc += a_sh[i] * hb[(size_t)i * 512];
            ws[OFF_CP + ((size_t)b * 4 + tc) * 512 + tid] = acc;
        }
        grid.sync();

        // ---- P4: ctx combine + composed head + softmax/argmax/lens + x update ----
        if (blk < 64) {
            const int b = blk;
            float ctx = 0.0f;
#pragma unroll
            for (int tc = 0; tc < 4; ++tc) ctx += ws[OFF_CP + ((size_t)b * 4 + tc) * 512 + tid];
            feat[512 + tid] = ctx;
            ws[OFF_XT + (size_t)(64 + tid) * 64 + b] = ctx;
            feat[tid] = ws[OFF_XT + (size_t)(hs_out + tid) * 64 + b];
            __syncthreads();
            int v = tid >> 3, q = tid & 7;
            const float4* w4 = (const float4*)(ws + OFF_W2 + (size_t)v * 1024 + q * 128);
            const float4* f4 = (const float4*)feat + q * 32;
            float acc = 0.0f;
#pragma unroll 8
            for (int k2 = 0; k2 < 32; ++k2) acc += dot4(w4[k2], f4[k2]);
            acc += __shfl_xor(acc, 1);
            acc += __shfl_xor(acc, 2);
            acc += __shfl_xor(acc, 4);
            if (q == 0) lg_s[v] = acc;
            __syncthreads();
            if (tid < 64) {
                float lg = lg_s[tid] + ws[OFF_B2 + tid];
                float mxv = lg;
#pragma unroll
                for (int mm = 1; mm < 64; mm <<= 1) mxv = fmaxf(mxv, __shfl_xor(mxv, mm));
                float ev = __expf(lg - mxv);
                float s = ev;
#pragma unroll
                for (int mm = 1; mm < 64; mm <<= 1) s += __shfl_xor(s, mm);
                float y = ev / s;
                out[OUT_YH + (size_t)b * 8192 + ts * 64 + tid] = y;
                ws[OFF_XT + (size_t)tid * 64 + b] = y;
                float av = lg;
                int ai = tid;
#pragma unroll
                for (int mm = 1; mm < 64; mm <<= 1) {
                    float ov = __shfl_xor(av, mm);
                    int oi = __shfl_xor(ai, mm);
                    if (ov > av || (ov == av && oi < ai)) { av = ov; ai = oi; }
                }
                if (tid == 0) {
                    int* lens = (int*)ws + OFF_LENS;
                    if (ai == 1 && lens[b] > ts) lens[b] = ts + 1;   // EOS == 1
                }
            }
        }
        grid.sync();
    }

    if (blk == 0 && tid < 64)
        out[OUT_LENS + tid] = (float)(((const int*)ws)[OFF_LENS + tid]);
}

extern "C" void kernel_launch(void* const* d_in, const int* in_sizes, int n_in,
                              void* d_out, int out_size, void* d_ws, size_t ws_size,
                              hipStream_t stream) {
    (void)in_sizes; (void)n_in; (void)out_size; (void)ws_size;
    const float* h    = (const float*)d_in[0];
    const float* Wih  = (const float*)d_in[1];
    const float* Whh  = (const float*)d_in[2];
    const float* bih  = (const float*)d_in[3];
    const float* bhh  = (const float*)d_in[4];
    const float* fc1w = (const float*)d_in[5];
    const float* fc1b = (const float*)d_in[6];
    const float* fc2w = (const float*)d_in[7];
    const int*   slen = (const int*)d_in[8];
    float* ws  = (float*)d_ws;
    float* out = (float*)d_out;

    void* args[] = { (void*)&h, (void*)&Wih, (void*)&Whh, (void*)&bih, (void*)&bhh,
                     (void*)&fc1w, (void*)&fc1b, (void*)&fc2w, (void*)&slen,
                     (void*)&ws, (void*)&out };
    hipLaunchCooperativeKernel((const void*)mega, dim3(NBLK), dim3(NTHR), args, 0, stream);
}

// Round 6
// 18077.667 us; speedup vs baseline: 1.5112x; 1.5112x over previous
//
#include <hip/hip_runtime.h>
#include <hip/hip_cooperative_groups.h>
#include <math.h>

namespace cg = cooperative_groups;

#define NBLK 256
#define NTHR 512

// ws offsets (floats)
#define OFF_XT   0          // XT[1600][64]: 0..63 y^T, 64..575 ctx^T, 576..1087 hs ping, 1088..1599 hs pong
#define OFF_CS   102400     // cs^T [512][64]
#define OFF_E    135168     // e[64][1024]
#define OFF_MD   200704     // [64][4][2] per-slice {m, D}
#define OFF_LENS 201216     // int[64]
#define OFF_W2   201280     // W2[64][1024] = fc2w @ fc1w
#define OFF_B2   266816     // b2[64]
#define OFF_CP   266880     // N partials [64 b][4 slice][512 d]  (ends 397952 fl = 1.59 MB)

// out offsets (floats)
#define OUT_YH   0          // [64][128][64]
#define OUT_LENS 524288     // [64]
#define OUT_ATT  524352     // [64][1][128][1024]

__device__ __forceinline__ float sigf(float x) { return 1.0f / (1.0f + __expf(-x)); }
__device__ __forceinline__ float dot4(float4 a, float4 b) {
    return a.x * b.x + a.y * b.y + a.z * b.z + a.w * b.w;
}

__global__ __launch_bounds__(NTHR, 1) void mega(
    const float* __restrict__ h, const float* __restrict__ Wih,
    const float* __restrict__ Whh, const float* __restrict__ bih,
    const float* __restrict__ bhh, const float* __restrict__ fc1w,
    const float* __restrict__ fc1b, const float* __restrict__ fc2w,
    const int* __restrict__ slen, float* ws, float* __restrict__ out)
{
    cg::grid_group grid = cg::this_grid();
    const int blk = blockIdx.x;
    const int tid = threadIdx.x;
    const int lane = tid & 63;
    const int w = tid >> 6;

    __shared__ float smem[8720];
    float* stage = smem;            // [8192]  P2 staging (16 rows x 512)
    float* hs_sh = smem + 8192;     // [512]
    float* e_sh  = smem + 8704;     // [16]
    // P1 alias: gpart[w][uu][g][b] -> smem[((w*2+uu)*4+g)*64+b]   (4096 fl)
    // P3 alias: red = smem[0..511]; feat = smem[512..1535]; sc_sh = smem[1536..1539]; lg_s = smem[1544..1607]

    // ---------------- init ----------------
    if (blk < 200) {                         // XT: 1600*64 = 102400 = 200*512
        int idx = blk * 512 + tid;
        int k = idx >> 6, b = idx & 63;
        float v = 0.0f;
        if (k == 0) v = 1.0f;                                    // one-hot SOS
        else if (k >= 64 && k < 576) v = h[(size_t)b * 524288 + (k - 64)];
        ws[OFF_XT + idx] = v;                                    // hs ping/pong rows -> 0
    }
    if (blk >= 128 && blk < 192)             // CS: 32768 = 64*512
        ws[OFF_CS + (blk - 128) * 512 + tid] = 0.0f;
    if (blk < 128) {                         // W2 = fc2w @ fc1w : 64v x 1024k
        int v = blk >> 1, kk = (blk & 1) * 512 + tid;
        float a = 0.0f;
        for (int m = 0; m < 128; ++m) a += fc2w[v * 128 + m] * fc1w[(size_t)m * 1024 + kk];
        ws[OFF_W2 + (size_t)v * 1024 + kk] = a;
    }
    if (blk == 255 && tid < 64) {
        float a = 0.0f;
        for (int m = 0; m < 128; ++m) a += fc2w[tid * 128 + m] * fc1b[m];
        ws[OFF_B2 + tid] = a;
        ((int*)ws)[OFF_LENS + tid] = 128;
    }
    grid.sync();

    for (int ts = 0; ts < 128; ++ts) {
        const int hs_in  = 576 + ((ts & 1) ? 512 : 0);
        const int hs_out = 576 + ((ts & 1) ? 0 : 512);

        // ---- P1: gates (8 waves x K-eighth) + LSTM cell (all 256 blocks) ----
        {
            const int u0 = blk * 2;
            const int wq = __builtin_amdgcn_readfirstlane(w);
            float acc[2][4] = {{0, 0, 0, 0}, {0, 0, 0, 0}};
            int k0 = wq * 136, k1 = k0 + 136;
            int kx1 = k1 < 576 ? k1 : 576;
#pragma unroll 8
            for (int k = k0; k < kx1; ++k) {
                float xv = ws[OFF_XT + k * 64 + lane];
#pragma unroll
                for (int uu = 0; uu < 2; ++uu)
#pragma unroll
                    for (int g = 0; g < 4; ++g)
                        acc[uu][g] += Wih[(size_t)(g * 512 + u0 + uu) * 576 + k] * xv;
            }
            int kh0 = k0 > 576 ? k0 : 576;
#pragma unroll 8
            for (int k = kh0; k < k1; ++k) {
                float xv = ws[OFF_XT + (hs_in + (k - 576)) * 64 + lane];
#pragma unroll
                for (int uu = 0; uu < 2; ++uu)
#pragma unroll
                    for (int g = 0; g < 4; ++g)
                        acc[uu][g] += Whh[(size_t)(g * 512 + u0 + uu) * 512 + (k - 576)] * xv;
            }
#pragma unroll
            for (int uu = 0; uu < 2; ++uu)
#pragma unroll
                for (int g = 0; g < 4; ++g)
                    smem[((w * 2 + uu) * 4 + g) * 64 + lane] = acc[uu][g];
            __syncthreads();
            if (tid < 128) {
                int uu = tid >> 6, b = tid & 63;
                int u = u0 + uu;
                float g4[4];
#pragma unroll
                for (int g = 0; g < 4; ++g) {
                    float s = 0.0f;
#pragma unroll
                    for (int ww = 0; ww < 8; ++ww) s += smem[((ww * 2 + uu) * 4 + g) * 64 + b];
                    g4[g] = s + bih[g * 512 + u] + bhh[g * 512 + u];
                }
                int idx = u * 64 + b;
                float co = ws[OFF_CS + idx];
                float I = sigf(g4[0]), F = sigf(g4[1]), G = tanhf(g4[2]), O = sigf(g4[3]);
                float cn = F * co + I * G;
                ws[OFF_CS + idx] = cn;
                ws[OFF_XT + (size_t)(hs_out + u) * 64 + b] = O * tanhf(cn);
            }
        }
        grid.sync();

        // ---- P2: fused e + online-softmax ctx partials (all 256 blocks) ----
        {
            const int b = blk >> 2, sb = blk & 3;
            const int L = slen[b];
            const int t0 = sb * 256;
            const float* hb = h + ((size_t)b * 1024 + t0) * 512;
            hs_sh[tid] = ws[OFF_XT + (size_t)(hs_out + tid) * 64 + b];
            __syncthreads();
            float hsv[8];
#pragma unroll
            for (int j = 0; j < 8; ++j) hsv[j] = hs_sh[lane * 8 + j];
            float m_run = -INFINITY, D = 0.0f, acc = 0.0f;
            for (int c = 0; c < 16; ++c) {
                // stage 16 rows (32KB): 4 x float4 per thread, back-to-back
                const float* gsrc = hb + (size_t)c * 8192 + tid * 4;
                float4 tv0 = *(const float4*)(gsrc);
                float4 tv1 = *(const float4*)(gsrc + 2048);
                float4 tv2 = *(const float4*)(gsrc + 4096);
                float4 tv3 = *(const float4*)(gsrc + 6144);
                __syncthreads();             // previous chunk fully consumed
                *(float4*)&stage[tid * 4]        = tv0;
                *(float4*)&stage[2048 + tid * 4] = tv1;
                *(float4*)&stage[4096 + tid * 4] = tv2;
                *(float4*)&stage[6144 + tid * 4] = tv3;
                __syncthreads();
                // e for 16 rows (2 per wave)
#pragma unroll
                for (int rr = 0; rr < 2; ++rr) {
                    int tl = w * 2 + rr;
                    const float4* rp = (const float4*)&stage[tl * 512 + lane * 8];
                    float4 p = rp[0], q = rp[1];
                    float part = p.x * hsv[0] + p.y * hsv[1] + p.z * hsv[2] + p.w * hsv[3]
                               + q.x * hsv[4] + q.y * hsv[5] + q.z * hsv[6] + q.w * hsv[7];
#pragma unroll
                    for (int mm = 1; mm < 64; mm <<= 1) part += __shfl_xor(part, mm);
                    if (lane == 0) {
                        e_sh[tl] = part;
                        ws[OFF_E + (size_t)b * 1024 + t0 + c * 16 + tl] = part;
                    }
                }
                __syncthreads();
                // online rescale + accumulate (thread owns d = tid)
                float cm = e_sh[0];
#pragma unroll
                for (int j = 1; j < 16; ++j) cm = fmaxf(cm, e_sh[j]);
                float m_new = fmaxf(m_run, cm);
                float sc = __expf(m_run - m_new);   // -inf -> 0 on first chunk
                acc *= sc; D *= sc;
                m_run = m_new;
#pragma unroll
                for (int tl = 0; tl < 16; ++tl) {
                    int tg = t0 + c * 16 + tl;
                    float wt = (tg < L) ? __expf(e_sh[tl] - m_run) : 0.0f;
                    D += wt;
                    acc += wt * stage[tl * 512 + tid];
                }
            }
            ws[OFF_CP + (size_t)(b * 4 + sb) * 512 + tid] = acc;
            if (tid == 0) {
                ws[OFF_MD + (b * 4 + sb) * 2]     = m_run;
                ws[OFF_MD + (b * 4 + sb) * 2 + 1] = D;
            }
        }
        grid.sync();

        // ---- P3: combine (global max) + attentions + head + lens + x update ----
        if (blk < 64) {
            const int b = blk;
            float* red   = smem;          // [512]
            float* feat  = smem + 512;    // [1024]
            float* sc_sh = smem + 1536;   // [4]
            float* lg_s  = smem + 1544;   // [64]
            red[tid] = (tid < 256) ? ws[OFF_MD + tid * 2] : -INFINITY;
            __syncthreads();
            for (int s = 256; s > 0; s >>= 1) {
                if (tid < s) red[tid] = fmaxf(red[tid], red[tid + s]);
                __syncthreads();
            }
            float m_g = red[0];
            __syncthreads();
            if (tid < 4) {
                float mi = ws[OFF_MD + (b * 4 + tid) * 2];
                float Di = ws[OFF_MD + (b * 4 + tid) * 2 + 1];
                float s = __expf(mi - m_g);
                sc_sh[tid] = s;
                red[tid] = s * Di;
            }
            __syncthreads();
            float dn = red[0] + red[1] + red[2] + red[3];
            float inv = 1.0f / (dn + 1e-5f);
            float cx = 0.0f;
#pragma unroll
            for (int i = 0; i < 4; ++i)
                cx += sc_sh[i] * ws[OFF_CP + (size_t)(b * 4 + i) * 512 + tid];
            cx *= inv;
            feat[512 + tid] = cx;
            ws[OFF_XT + (size_t)(64 + tid) * 64 + b] = cx;
            feat[tid] = ws[OFF_XT + (size_t)(hs_out + tid) * 64 + b];
            int L = slen[b];
#pragma unroll
            for (int q = 0; q < 2; ++q) {
                int t = tid + 512 * q;
                float e = ws[OFF_E + (size_t)b * 1024 + t];
                float a = (t < L) ? __expf(e - m_g) * inv : 0.0f;
                out[OUT_ATT + (size_t)b * 131072 + (size_t)ts * 1024 + t] = a;
            }
            __syncthreads();
            int v = tid >> 3, qq = tid & 7;
            const float4* w4 = (const float4*)(ws + OFF_W2 + (size_t)v * 1024 + qq * 128);
            const float4* f4 = (const float4*)feat + qq * 32;
            float acc = 0.0f;
#pragma unroll 8
            for (int k = 0; k < 32; ++k) acc += dot4(w4[k], f4[k]);
            acc += __shfl_xor(acc, 1);
            acc += __shfl_xor(acc, 2);
            acc += __shfl_xor(acc, 4);
            if (qq == 0) lg_s[v] = acc;
            __syncthreads();
            if (tid < 64) {
                float lg = lg_s[tid] + ws[OFF_B2 + tid];
                float mxv = lg;
#pragma unroll
                for (int mm = 1; mm < 64; mm <<= 1) mxv = fmaxf(mxv, __shfl_xor(mxv, mm));
                float ev = __expf(lg - mxv);
                float s = ev;
#pragma unroll
                for (int mm = 1; mm < 64; mm <<= 1) s += __shfl_xor(s, mm);
                float y = ev / s;
                out[OUT_YH + (size_t)b * 8192 + ts * 64 + tid] = y;
                ws[OFF_XT + (size_t)tid * 64 + b] = y;
                float av = lg;
                int ai = tid;
#pragma unroll
                for (int mm = 1; mm < 64; mm <<= 1) {
                    float ov = __shfl_xor(av, mm);
                    int oi = __shfl_xor(ai, mm);
                    if (ov > av || (ov == av && oi < ai)) { av = ov; ai = oi; }
                }
                if (tid == 0) {
                    int* lens = (int*)ws + OFF_LENS;
                    if (ai == 1 && lens[b] > ts) lens[b] = ts + 1;   // EOS == 1
                }
            }
        }
        grid.sync();
    }

    if (blk == 0 && tid < 64)
        out[OUT_LENS + tid] = (float)(((const int*)ws)[OFF_LENS + tid]);
}

extern "C" void kernel_launch(void* const* d_in, const int* in_sizes, int n_in,
                              void* d_out, int out_size, void* d_ws, size_t ws_size,
                              hipStream_t stream) {
    (void)in_sizes; (void)n_in; (void)out_size; (void)ws_size;
    const float* h    = (const float*)d_in[0];
    const float* Wih  = (const float*)d_in[1];
    const float* Whh  = (const float*)d_in[2];
    const float* bih  = (const float*)d_in[3];
    const float* bhh  = (const float*)d_in[4];
    const float* fc1w = (const float*)d_in[5];
    const float* fc1b = (const float*)d_in[6];
    const float* fc2w = (const float*)d_in[7];
    const int*   slen = (const int*)d_in[8];
    float* ws  = (float*)d_ws;
    float* out = (float*)d_out;

    void* args[] = { (void*)&h, (void*)&Wih, (void*)&Whh, (void*)&bih, (void*)&bhh,
                     (void*)&fc1w, (void*)&fc1b, (void*)&fc2w, (void*)&slen,
                     (void*)&ws, (void*)&out };
    hipLaunchCooperativeKernel((const void*)mega, dim3(NBLK), dim3(NTHR), args, 0, stream);
}

// Round 7
// 9259.173 us; speedup vs baseline: 2.9504x; 1.9524x over previous
//
#include <hip/hip_runtime.h>
#include <math.h>

// ws offsets (floats)
#define OFF_XT   0          // XT[1600][64]: 0..63 y^T, 64..575 ctx^T, 576..1087 hs ping, 1088..1599 hs pong
#define OFF_CS   102400     // cs^T [512][64]
#define OFF_E    135168     // e[64][1024]
#define OFF_MD   200704     // [64][16][2] per-slice {m, D}
#define OFF_LENS 202752     // int[64]
#define OFF_W2   202816     // W2[64][1024] = fc2w @ fc1w
#define OFF_B2   268352     // b2[64]
#define OFF_CP   268416     // N partials [64 b][16 slice][512 d] (ends 792704 fl = 3.17 MB)

// out offsets (floats)
#define OUT_YH   0          // [64][128][64]
#define OUT_LENS 524288     // [64]
#define OUT_ATT  524352     // [64][1][128][1024]

__device__ __forceinline__ float sigf(float x) { return 1.0f / (1.0f + __expf(-x)); }
__device__ __forceinline__ float dot4(float4 a, float4 b) {
    return a.x * b.x + a.y * b.y + a.z * b.z + a.w * b.w;
}

// ---------------- init: XT, CS, lens ----------------
__global__ void k_init(const float* __restrict__ h, float* __restrict__ ws) {
    int blk = blockIdx.x, tid = threadIdx.x;      // grid 528 x 256
    int idx = blk * 256 + tid;
    if (idx < 102400) {                           // XT: 1600*64
        int k = idx >> 6, b = idx & 63;
        float v = 0.0f;
        if (k == 0) v = 1.0f;                                    // one-hot SOS
        else if (k >= 64 && k < 576) v = h[(size_t)b * 524288 + (k - 64)];
        ws[OFF_XT + idx] = v;                                    // hs ping/pong rows -> 0
    }
    if (blk >= 400 && blk < 528)                  // CS: 32768 = 128*256
        ws[OFF_CS + (blk - 400) * 256 + tid] = 0.0f;
    if (blk == 527 && tid < 64) ((int*)ws)[OFF_LENS + tid] = 128;
}

// ---------------- fc2 o fc1 composition (once) ----------------
__global__ void k_fuse(const float* __restrict__ fc1w, const float* __restrict__ fc1b,
                       const float* __restrict__ fc2w, float* __restrict__ ws) {
    int blk = blockIdx.x;                         // 256 blocks
    int v = blk >> 2, kc = blk & 3;
    int k = kc * 256 + threadIdx.x;
    float acc = 0.0f;
#pragma unroll 8
    for (int m = 0; m < 128; m++) acc += fc2w[v * 128 + m] * fc1w[(size_t)m * 1024 + k];
    ws[OFF_W2 + (size_t)v * 1024 + k] = acc;
    if (kc == 0 && threadIdx.x == 0) {
        float bb = 0.0f;
        for (int m = 0; m < 128; m++) bb += fc2w[v * 128 + m] * fc1b[m];
        ws[OFF_B2 + v] = bb;
    }
}

// ---------------- gates (8 waves x K-eighth) + LSTM cell ----------------
// grid 256 x 512
__global__ void k_gates(const float* __restrict__ Wih, const float* __restrict__ Whh,
                        const float* __restrict__ bih, const float* __restrict__ bhh,
                        float* __restrict__ ws, int p) {
    const int tid = threadIdx.x;
    const int lane = tid & 63;
    const int w = tid >> 6;
    const int hs_in  = 576 + (p ? 512 : 0);
    const int hs_out = 576 + (p ? 0 : 512);
    __shared__ float gpart[4096];
    const int u0 = blockIdx.x * 2;
    const int wq = __builtin_amdgcn_readfirstlane(w);
    float acc[2][4] = {{0, 0, 0, 0}, {0, 0, 0, 0}};
    int k0 = wq * 136, k1 = k0 + 136;
    int kx1 = k1 < 576 ? k1 : 576;
#pragma unroll 8
    for (int k = k0; k < kx1; ++k) {
        float xv = ws[OFF_XT + k * 64 + lane];
#pragma unroll
        for (int uu = 0; uu < 2; ++uu)
#pragma unroll
            for (int g = 0; g < 4; ++g)
                acc[uu][g] += Wih[(size_t)(g * 512 + u0 + uu) * 576 + k] * xv;
    }
    int kh0 = k0 > 576 ? k0 : 576;
#pragma unroll 8
    for (int k = kh0; k < k1; ++k) {
        float xv = ws[OFF_XT + (hs_in + (k - 576)) * 64 + lane];
#pragma unroll
        for (int uu = 0; uu < 2; ++uu)
#pragma unroll
            for (int g = 0; g < 4; ++g)
                acc[uu][g] += Whh[(size_t)(g * 512 + u0 + uu) * 512 + (k - 576)] * xv;
    }
#pragma unroll
    for (int uu = 0; uu < 2; ++uu)
#pragma unroll
        for (int g = 0; g < 4; ++g)
            gpart[((w * 2 + uu) * 4 + g) * 64 + lane] = acc[uu][g];
    __syncthreads();
    if (tid < 128) {
        int uu = tid >> 6, b = tid & 63;
        int u = u0 + uu;
        float g4[4];
#pragma unroll
        for (int g = 0; g < 4; ++g) {
            float s = 0.0f;
#pragma unroll
            for (int ww = 0; ww < 8; ++ww) s += gpart[((ww * 2 + uu) * 4 + g) * 64 + b];
            g4[g] = s + bih[g * 512 + u] + bhh[g * 512 + u];
        }
        int idx = u * 64 + b;
        float co = ws[OFF_CS + idx];
        float I = sigf(g4[0]), F = sigf(g4[1]), G = tanhf(g4[2]), O = sigf(g4[3]);
        float cn = F * co + I * G;
        ws[OFF_CS + idx] = cn;
        ws[OFF_XT + (size_t)(hs_out + u) * 64 + b] = O * tanhf(cn);
    }
}

// ---------------- fused e + online-softmax ctx partials ----------------
// grid 1024 = b*16 + sb, block 256 (4 waves); slice = 64 t-rows, chunk = 8 rows
__global__ void k_attn(const float* __restrict__ h, const int* __restrict__ slen,
                       float* __restrict__ ws, int p) {
    const int blk = blockIdx.x;
    const int tid = threadIdx.x;
    const int lane = tid & 63;
    const int w = tid >> 6;
    const int hs_out = 576 + (p ? 0 : 512);
    const int b = blk >> 4, sb = blk & 15;
    const int L = slen[b];
    const int t0 = sb * 64;
    __shared__ float stage[4096];   // 8 rows x 512
    __shared__ float hs_sh[512];
    __shared__ float e_sh[8];
    const float* hb = h + ((size_t)b * 1024 + t0) * 512;
    hs_sh[tid]       = ws[OFF_XT + (size_t)(hs_out + tid) * 64 + b];
    hs_sh[256 + tid] = ws[OFF_XT + (size_t)(hs_out + 256 + tid) * 64 + b];
    __syncthreads();
    float hsv[8];
#pragma unroll
    for (int j = 0; j < 8; ++j) hsv[j] = hs_sh[lane * 8 + j];
    float m_run = -INFINITY, D = 0.0f, accx = 0.0f, accy = 0.0f;
    for (int c = 0; c < 8; ++c) {
        // stage 8 rows (16KB): 4 back-to-back float4 loads per thread
        const float* gsrc = hb + (size_t)c * 4096 + tid * 4;
        float4 tv0 = *(const float4*)(gsrc);
        float4 tv1 = *(const float4*)(gsrc + 1024);
        float4 tv2 = *(const float4*)(gsrc + 2048);
        float4 tv3 = *(const float4*)(gsrc + 3072);
        __syncthreads();             // previous chunk fully consumed
        *(float4*)&stage[tid * 4]        = tv0;
        *(float4*)&stage[1024 + tid * 4] = tv1;
        *(float4*)&stage[2048 + tid * 4] = tv2;
        *(float4*)&stage[3072 + tid * 4] = tv3;
        __syncthreads();
        // e for 8 rows (2 per wave)
#pragma unroll
        for (int rr = 0; rr < 2; ++rr) {
            int tl = w * 2 + rr;
            const float4* rp = (const float4*)&stage[tl * 512 + lane * 8];
            float4 pp = rp[0], qq = rp[1];
            float part = pp.x * hsv[0] + pp.y * hsv[1] + pp.z * hsv[2] + pp.w * hsv[3]
                       + qq.x * hsv[4] + qq.y * hsv[5] + qq.z * hsv[6] + qq.w * hsv[7];
#pragma unroll
            for (int mm = 1; mm < 64; mm <<= 1) part += __shfl_xor(part, mm);
            if (lane == 0) {
                e_sh[tl] = part;
                ws[OFF_E + (size_t)b * 1024 + t0 + c * 8 + tl] = part;
            }
        }
        __syncthreads();
        // online rescale + accumulate (thread owns d-pair 2*tid)
        float cm = e_sh[0];
#pragma unroll
        for (int j = 1; j < 8; ++j) cm = fmaxf(cm, e_sh[j]);
        float m_new = fmaxf(m_run, cm);
        float sc = __expf(m_run - m_new);   // -inf -> 0 on first chunk
        accx *= sc; accy *= sc; D *= sc;
        m_run = m_new;
#pragma unroll
        for (int tl = 0; tl < 8; ++tl) {
            int tg = t0 + c * 8 + tl;
            float wt = (tg < L) ? __expf(e_sh[tl] - m_run) : 0.0f;
            D += wt;
            float2 hv = *(const float2*)&stage[tl * 512 + tid * 2];
            accx += wt * hv.x;
            accy += wt * hv.y;
        }
    }
    float2 o2; o2.x = accx; o2.y = accy;
    *(float2*)&ws[OFF_CP + (size_t)(b * 16 + sb) * 512 + tid * 2] = o2;
    if (tid == 0) {
        ws[OFF_MD + (b * 16 + sb) * 2]     = m_run;
        ws[OFF_MD + (b * 16 + sb) * 2 + 1] = D;
    }
}

// ---------------- combine (global max) + attentions + head + lens + x update ----
// grid 64 x 256
__global__ void k_comb(const int* __restrict__ slen, float* __restrict__ ws,
                       float* __restrict__ out, int p, int ts) {
    const int b = blockIdx.x, tid = threadIdx.x;
    const int hs_out = 576 + (p ? 0 : 512);
    __shared__ float red[256];
    __shared__ float feat[1024];
    __shared__ float sc_sh[16];
    __shared__ float lg_s[64];
    float mx = -INFINITY;
#pragma unroll
    for (int i = 0; i < 4; ++i) mx = fmaxf(mx, ws[OFF_MD + (tid + 256 * i) * 2]);
    red[tid] = mx;
    __syncthreads();
    for (int s = 128; s > 0; s >>= 1) {
        if (tid < s) red[tid] = fmaxf(red[tid], red[tid + s]);
        __syncthreads();
    }
    float m_g = red[0];
    __syncthreads();
    if (tid < 16) {
        float mi = ws[OFF_MD + (b * 16 + tid) * 2];
        float Di = ws[OFF_MD + (b * 16 + tid) * 2 + 1];
        float s = __expf(mi - m_g);
        sc_sh[tid] = s;
        red[tid] = s * Di;
    }
    __syncthreads();
    float dn = 0.0f;
#pragma unroll
    for (int j = 0; j < 16; ++j) dn += red[j];
    float inv = 1.0f / (dn + 1e-5f);
    float cx = 0.0f, cy = 0.0f;
#pragma unroll 4
    for (int i = 0; i < 16; ++i) {
        float s = sc_sh[i];
        float2 v = *(const float2*)&ws[OFF_CP + (size_t)(b * 16 + i) * 512 + tid * 2];
        cx += s * v.x;
        cy += s * v.y;
    }
    cx *= inv; cy *= inv;
    feat[512 + tid * 2] = cx;
    feat[512 + tid * 2 + 1] = cy;
    ws[OFF_XT + (size_t)(64 + tid * 2) * 64 + b] = cx;
    ws[OFF_XT + (size_t)(64 + tid * 2 + 1) * 64 + b] = cy;
    feat[tid * 2]     = ws[OFF_XT + (size_t)(hs_out + tid * 2) * 64 + b];
    feat[tid * 2 + 1] = ws[OFF_XT + (size_t)(hs_out + tid * 2 + 1) * 64 + b];
    int L = slen[b];
#pragma unroll
    for (int q = 0; q < 4; ++q) {
        int t = tid + 256 * q;
        float e = ws[OFF_E + (size_t)b * 1024 + t];
        float a = (t < L) ? __expf(e - m_g) * inv : 0.0f;
        out[OUT_ATT + (size_t)b * 131072 + (size_t)ts * 1024 + t] = a;
    }
    __syncthreads();
    int v = tid >> 2, qq = tid & 3;
    const float4* w4 = (const float4*)(ws + OFF_W2 + (size_t)v * 1024 + qq * 256);
    const float4* f4 = (const float4*)feat + qq * 64;
    float acc = 0.0f;
#pragma unroll 8
    for (int k = 0; k < 64; ++k) acc += dot4(w4[k], f4[k]);
    acc += __shfl_xor(acc, 1);
    acc += __shfl_xor(acc, 2);
    if (qq == 0) lg_s[v] = acc;
    __syncthreads();
    if (tid < 64) {
        float lg = lg_s[tid] + ws[OFF_B2 + tid];
        float mxv = lg;
#pragma unroll
        for (int mm = 1; mm < 64; mm <<= 1) mxv = fmaxf(mxv, __shfl_xor(mxv, mm));
        float ev = __expf(lg - mxv);
        float s = ev;
#pragma unroll
        for (int mm = 1; mm < 64; mm <<= 1) s += __shfl_xor(s, mm);
        float y = ev / s;
        out[OUT_YH + (size_t)b * 8192 + ts * 64 + tid] = y;
        ws[OFF_XT + (size_t)tid * 64 + b] = y;
        float av = lg;
        int ai = tid;
#pragma unroll
        for (int mm = 1; mm < 64; mm <<= 1) {
            float ov = __shfl_xor(av, mm);
            int oi = __shfl_xor(ai, mm);
            if (ov > av || (ov == av && oi < ai)) { av = ov; ai = oi; }
        }
        if (tid == 0) {
            int* lens = (int*)ws + OFF_LENS;
            if (ai == 1 && lens[b] > ts) lens[b] = ts + 1;   // EOS == 1
        }
    }
}

__global__ void k_lens(const float* __restrict__ ws, float* __restrict__ out) {
    int tid = threadIdx.x;   // 64
    out[OUT_LENS + tid] = (float)(((const int*)ws)[OFF_LENS + tid]);
}

extern "C" void kernel_launch(void* const* d_in, const int* in_sizes, int n_in,
                              void* d_out, int out_size, void* d_ws, size_t ws_size,
                              hipStream_t stream) {
    (void)in_sizes; (void)n_in; (void)out_size; (void)ws_size;
    const float* h    = (const float*)d_in[0];
    const float* Wih  = (const float*)d_in[1];
    const float* Whh  = (const float*)d_in[2];
    const float* bih  = (const float*)d_in[3];
    const float* bhh  = (const float*)d_in[4];
    const float* fc1w = (const float*)d_in[5];
    const float* fc1b = (const float*)d_in[6];
    const float* fc2w = (const float*)d_in[7];
    const int*   slen = (const int*)d_in[8];
    float* ws  = (float*)d_ws;
    float* out = (float*)d_out;

    k_init<<<528, 256, 0, stream>>>(h, ws);
    k_fuse<<<256, 256, 0, stream>>>(fc1w, fc1b, fc2w, ws);
    for (int t = 0; t < 128; t++) {
        int p = t & 1;
        k_gates<<<256, 512, 0, stream>>>(Wih, Whh, bih, bhh, ws, p);
        k_attn<<<1024, 256, 0, stream>>>(h, slen, ws, p);
        k_comb<<<64, 256, 0, stream>>>(slen, ws, out, p, t);
    }
    k_lens<<<1, 64, 0, stream>>>(ws, out);
}

// Round 8
// 6519.243 us; speedup vs baseline: 4.1905x; 1.4203x over previous
//
#include <hip/hip_runtime.h>
#include <math.h>

typedef unsigned short ushort_t;
typedef unsigned int uint_t;

// ws offsets (floats)
#define OFF_XT    0          // XT[1600][64]: 0..63 y^T, 64..575 ctx^T, 576..1087 hs ping, 1088..1599 hs pong
#define OFF_CS    102400     // cs^T [512][64]
#define OFF_E     135168     // e[64][1024]
#define OFF_MD    200704     // [64][16][2] per-slice {m, D}
#define OFF_LENS  202752     // int[64]
#define OFF_W2    202816     // W2[64][1024] = fc2w @ fc1w
#define OFF_B2    268352     // b2[64]
#define OFF_CP    268416     // N partials [64 b][16 slice][512 d] (ends 792704)
#define OFF_HB16F 793600     // h in bf16: 33,554,432 ushorts = 16,777,216 floats
#define WS_NEED   ((size_t)(793600 + 16777216) * 4)

// out offsets (floats)
#define OUT_YH   0          // [64][128][64]
#define OUT_LENS 524288     // [64]
#define OUT_ATT  524352     // [64][1][128][1024]

__device__ __forceinline__ float sigf(float x) { return 1.0f / (1.0f + __expf(-x)); }
__device__ __forceinline__ float dot4(float4 a, float4 b) {
    return a.x * b.x + a.y * b.y + a.z * b.z + a.w * b.w;
}
__device__ __forceinline__ uint_t bf16rne(float x) {
    uint_t u = __float_as_uint(x);
    return (u + 0x7FFFu + ((u >> 16) & 1u)) >> 16;
}
#define BLO(u) __uint_as_float((u) << 16)
#define BHI(u) __uint_as_float((u) & 0xFFFF0000u)

// ---------------- init: XT, CS, lens ----------------
__global__ void k_init(const float* __restrict__ h, float* __restrict__ ws) {
    int blk = blockIdx.x, tid = threadIdx.x;      // grid 528 x 256
    int idx = blk * 256 + tid;
    if (idx < 102400) {                           // XT: 1600*64
        int k = idx >> 6, b = idx & 63;
        float v = 0.0f;
        if (k == 0) v = 1.0f;                                    // one-hot SOS
        else if (k >= 64 && k < 576) v = h[(size_t)b * 524288 + (k - 64)];
        ws[OFF_XT + idx] = v;                                    // hs ping/pong rows -> 0
    }
    if (blk >= 400 && blk < 528)                  // CS: 32768 = 128*256
        ws[OFF_CS + (blk - 400) * 256 + tid] = 0.0f;
    if (blk == 527 && tid < 64) ((int*)ws)[OFF_LENS + tid] = 128;
}

// ---------------- h -> bf16 (once per launch) ----------------
__global__ void k_hconv(const float* __restrict__ h, float* __restrict__ ws) {
    size_t i = ((size_t)blockIdx.x * 256 + threadIdx.x) * 8;   // grid 16384 x 256
    float4 a = *(const float4*)(h + i);
    float4 b = *(const float4*)(h + i + 4);
    uint4 o;
    o.x = bf16rne(a.x) | (bf16rne(a.y) << 16);
    o.y = bf16rne(a.z) | (bf16rne(a.w) << 16);
    o.z = bf16rne(b.x) | (bf16rne(b.y) << 16);
    o.w = bf16rne(b.z) | (bf16rne(b.w) << 16);
    *(uint4*)((ushort_t*)(ws + OFF_HB16F) + i) = o;
}

// ---------------- fc2 o fc1 composition (once) ----------------
__global__ void k_fuse(const float* __restrict__ fc1w, const float* __restrict__ fc1b,
                       const float* __restrict__ fc2w, float* __restrict__ ws) {
    int blk = blockIdx.x;                         // 256 blocks
    int v = blk >> 2, kc = blk & 3;
    int k = kc * 256 + threadIdx.x;
    float acc = 0.0f;
#pragma unroll 8
    for (int m = 0; m < 128; m++) acc += fc2w[v * 128 + m] * fc1w[(size_t)m * 1024 + k];
    ws[OFF_W2 + (size_t)v * 1024 + k] = acc;
    if (kc == 0 && threadIdx.x == 0) {
        float bb = 0.0f;
        for (int m = 0; m < 128; m++) bb += fc2w[v * 128 + m] * fc1b[m];
        ws[OFF_B2 + v] = bb;
    }
}

// ---------------- gates (8 waves x K-eighth, float4 weights) + LSTM cell ----------------
// grid 256 x 512
__global__ void k_gates(const float* __restrict__ Wih, const float* __restrict__ Whh,
                        const float* __restrict__ bih, const float* __restrict__ bhh,
                        float* __restrict__ ws, int p) {
    const int tid = threadIdx.x;
    const int lane = tid & 63;
    const int w = tid >> 6;
    const int hs_in  = 576 + (p ? 512 : 0);
    const int hs_out = 576 + (p ? 0 : 512);
    __shared__ float gpart[4096];
    const int u0 = blockIdx.x * 2;
    const int wq = __builtin_amdgcn_readfirstlane(w);
    float acc[2][4] = {{0, 0, 0, 0}, {0, 0, 0, 0}};
    int k0 = wq * 136, k1 = k0 + 136;
    int kx1 = k1 < 576 ? k1 : 576;
#pragma unroll 2
    for (int k = k0; k < kx1; k += 4) {
        float4 xv;
        xv.x = ws[OFF_XT + (k + 0) * 64 + lane];
        xv.y = ws[OFF_XT + (k + 1) * 64 + lane];
        xv.z = ws[OFF_XT + (k + 2) * 64 + lane];
        xv.w = ws[OFF_XT + (k + 3) * 64 + lane];
#pragma unroll
        for (int uu = 0; uu < 2; ++uu)
#pragma unroll
            for (int g = 0; g < 4; ++g)
                acc[uu][g] += dot4(*(const float4*)&Wih[(size_t)(g * 512 + u0 + uu) * 576 + k], xv);
    }
    int kh0 = k0 > 576 ? k0 : 576;
#pragma unroll 2
    for (int k = kh0; k < k1; k += 4) {
        float4 xv;
        xv.x = ws[OFF_XT + (hs_in + (k - 576) + 0) * 64 + lane];
        xv.y = ws[OFF_XT + (hs_in + (k - 576) + 1) * 64 + lane];
        xv.z = ws[OFF_XT + (hs_in + (k - 576) + 2) * 64 + lane];
        xv.w = ws[OFF_XT + (hs_in + (k - 576) + 3) * 64 + lane];
#pragma unroll
        for (int uu = 0; uu < 2; ++uu)
#pragma unroll
            for (int g = 0; g < 4; ++g)
                acc[uu][g] += dot4(*(const float4*)&Whh[(size_t)(g * 512 + u0 + uu) * 512 + (k - 576)], xv);
    }
#pragma unroll
    for (int uu = 0; uu < 2; ++uu)
#pragma unroll
        for (int g = 0; g < 4; ++g)
            gpart[((w * 2 + uu) * 4 + g) * 64 + lane] = acc[uu][g];
    __syncthreads();
    if (tid < 128) {
        int uu = tid >> 6, b = tid & 63;
        int u = u0 + uu;
        float g4[4];
#pragma unroll
        for (int g = 0; g < 4; ++g) {
            float s = 0.0f;
#pragma unroll
            for (int ww = 0; ww < 8; ++ww) s += gpart[((ww * 2 + uu) * 4 + g) * 64 + b];
            g4[g] = s + bih[g * 512 + u] + bhh[g * 512 + u];
        }
        int idx = u * 64 + b;
        float co = ws[OFF_CS + idx];
        float I = sigf(g4[0]), F = sigf(g4[1]), G = tanhf(g4[2]), O = sigf(g4[3]);
        float cn = F * co + I * G;
        ws[OFF_CS + idx] = cn;
        ws[OFF_XT + (size_t)(hs_out + u) * 64 + b] = O * tanhf(cn);
    }
}

// ---------------- bf16 fused e + online-softmax ctx partials, double-buffered ----
// grid 1024 = b*16 + sb, block 256 (4 waves); slice = 64 t-rows, chunk = 16 rows
__global__ void k_attn16(const int* __restrict__ slen, float* __restrict__ ws, int p) {
    const int blk = blockIdx.x;
    const int tid = threadIdx.x;
    const int lane = tid & 63;
    const int w = tid >> 6;
    const int hs_out = 576 + (p ? 0 : 512);
    const int b = blk >> 4, sb = blk & 15;
    const int L = slen[b];
    const int t0 = sb * 64;
    __shared__ ushort_t stage[2][8192];   // 2 x 16 rows x 512
    __shared__ float hs_sh[512];
    __shared__ float e_sh[16];
    const ushort_t* hb = (const ushort_t*)(ws + OFF_HB16F) + ((size_t)b * 1024 + t0) * 512;
    // prologue: chunk-0 loads in flight, then hs
    uint4 r0 = *(const uint4*)(hb + tid * 8);
    uint4 r1 = *(const uint4*)(hb + 2048 + tid * 8);
    uint4 r2 = *(const uint4*)(hb + 4096 + tid * 8);
    uint4 r3 = *(const uint4*)(hb + 6144 + tid * 8);
    hs_sh[tid]       = ws[OFF_XT + (size_t)(hs_out + tid) * 64 + b];
    hs_sh[256 + tid] = ws[OFF_XT + (size_t)(hs_out + 256 + tid) * 64 + b];
    __syncthreads();
    float hsv[8];
#pragma unroll
    for (int j = 0; j < 8; ++j) hsv[j] = hs_sh[lane * 8 + j];
    float m_run = -INFINITY, D = 0.0f, accx = 0.0f, accy = 0.0f;
    int buf = 0;
    for (int c = 0; c < 4; ++c) {
        *(uint4*)&stage[buf][tid * 8]        = r0;
        *(uint4*)&stage[buf][tid * 8 + 2048] = r1;
        *(uint4*)&stage[buf][tid * 8 + 4096] = r2;
        *(uint4*)&stage[buf][tid * 8 + 6144] = r3;
        __syncthreads();                      // A: stage[buf] ready; prior reads of it long done
        if (c < 3) {                          // issue next chunk, consumed next iteration
            const ushort_t* g = hb + (size_t)(c + 1) * 8192;
            r0 = *(const uint4*)(g + tid * 8);
            r1 = *(const uint4*)(g + 2048 + tid * 8);
            r2 = *(const uint4*)(g + 4096 + tid * 8);
            r3 = *(const uint4*)(g + 6144 + tid * 8);
        }
        // e for 16 rows (4 per wave)
#pragma unroll
        for (int rr = 0; rr < 4; ++rr) {
            int tl = w * 4 + rr;
            uint4 hv = *(const uint4*)&stage[buf][tl * 512 + lane * 8];
            float part = BLO(hv.x) * hsv[0] + BHI(hv.x) * hsv[1]
                       + BLO(hv.y) * hsv[2] + BHI(hv.y) * hsv[3]
                       + BLO(hv.z) * hsv[4] + BHI(hv.z) * hsv[5]
                       + BLO(hv.w) * hsv[6] + BHI(hv.w) * hsv[7];
#pragma unroll
            for (int mm = 1; mm < 64; mm <<= 1) part += __shfl_xor(part, mm);
            if (lane == 0) {
                e_sh[tl] = part;
                ws[OFF_E + (size_t)b * 1024 + t0 + c * 16 + tl] = part;
            }
        }
        __syncthreads();                      // B: e_sh ready
        float cm = e_sh[0];
#pragma unroll
        for (int j = 1; j < 16; ++j) cm = fmaxf(cm, e_sh[j]);
        float m_new = fmaxf(m_run, cm);
        float sc = __expf(m_run - m_new);     // -inf -> 0 on first chunk
        accx *= sc; accy *= sc; D *= sc;
        m_run = m_new;
        const uint_t* st32 = (const uint_t*)&stage[buf][0];
#pragma unroll
        for (int tl = 0; tl < 16; ++tl) {
            int tg = t0 + c * 16 + tl;
            float wt = (tg < L) ? __expf(e_sh[tl] - m_run) : 0.0f;
            D += wt;
            uint_t v = st32[tl * 256 + tid];
            accx += wt * BLO(v);
            accy += wt * BHI(v);
        }
        buf ^= 1;
    }
    float2 o2; o2.x = accx; o2.y = accy;
    *(float2*)&ws[OFF_CP + (size_t)(b * 16 + sb) * 512 + tid * 2] = o2;
    if (tid == 0) {
        ws[OFF_MD + (b * 16 + sb) * 2]     = m_run;
        ws[OFF_MD + (b * 16 + sb) * 2 + 1] = D;
    }
}

// ---------------- f32 fallback attn (round-7, used if ws too small) ----------------
__global__ void k_attn(const float* __restrict__ h, const int* __restrict__ slen,
                       float* __restrict__ ws, int p) {
    const int blk = blockIdx.x;
    const int tid = threadIdx.x;
    const int lane = tid & 63;
    const int w = tid >> 6;
    const int hs_out = 576 + (p ? 0 : 512);
    const int b = blk >> 4, sb = blk & 15;
    const int L = slen[b];
    const int t0 = sb * 64;
    __shared__ float stage[4096];
    __shared__ float hs_sh[512];
    __shared__ float e_sh[8];
    const float* hb = h + ((size_t)b * 1024 + t0) * 512;
    hs_sh[tid]       = ws[OFF_XT + (size_t)(hs_out + tid) * 64 + b];
    hs_sh[256 + tid] = ws[OFF_XT + (size_t)(hs_out + 256 + tid) * 64 + b];
    __syncthreads();
    float hsv[8];
#pragma unroll
    for (int j = 0; j < 8; ++j) hsv[j] = hs_sh[lane * 8 + j];
    float m_run = -INFINITY, D = 0.0f, accx = 0.0f, accy = 0.0f;
    for (int c = 0; c < 8; ++c) {
        const float* gsrc = hb + (size_t)c * 4096 + tid * 4;
        float4 tv0 = *(const float4*)(gsrc);
        float4 tv1 = *(const float4*)(gsrc + 1024);
        float4 tv2 = *(const float4*)(gsrc + 2048);
        float4 tv3 = *(const float4*)(gsrc + 3072);
        __syncthreads();
        *(float4*)&stage[tid * 4]        = tv0;
        *(float4*)&stage[1024 + tid * 4] = tv1;
        *(float4*)&stage[2048 + tid * 4] = tv2;
        *(float4*)&stage[3072 + tid * 4] = tv3;
        __syncthreads();
#pragma unroll
        for (int rr = 0; rr < 2; ++rr) {
            int tl = w * 2 + rr;
            const float4* rp = (const float4*)&stage[tl * 512 + lane * 8];
            float4 pp = rp[0], qq = rp[1];
            float part = pp.x * hsv[0] + pp.y * hsv[1] + pp.z * hsv[2] + pp.w * hsv[3]
                       + qq.x * hsv[4] + qq.y * hsv[5] + qq.z * hsv[6] + qq.w * hsv[7];
#pragma unroll
            for (int mm = 1; mm < 64; mm <<= 1) part += __shfl_xor(part, mm);
            if (lane == 0) {
                e_sh[tl] = part;
                ws[OFF_E + (size_t)b * 1024 + t0 + c * 8 + tl] = part;
            }
        }
        __syncthreads();
        float cm = e_sh[0];
#pragma unroll
        for (int j = 1; j < 8; ++j) cm = fmaxf(cm, e_sh[j]);
        float m_new = fmaxf(m_run, cm);
        float sc = __expf(m_run - m_new);
        accx *= sc; accy *= sc; D *= sc;
        m_run = m_new;
#pragma unroll
        for (int tl = 0; tl < 8; ++tl) {
            int tg = t0 + c * 8 + tl;
            float wt = (tg < L) ? __expf(e_sh[tl] - m_run) : 0.0f;
            D += wt;
            float2 hv = *(const float2*)&stage[tl * 512 + tid * 2];
            accx += wt * hv.x;
            accy += wt * hv.y;
        }
    }
    float2 o2; o2.x = accx; o2.y = accy;
    *(float2*)&ws[OFF_CP + (size_t)(b * 16 + sb) * 512 + tid * 2] = o2;
    if (tid == 0) {
        ws[OFF_MD + (b * 16 + sb) * 2]     = m_run;
        ws[OFF_MD + (b * 16 + sb) * 2 + 1] = D;
    }
}

// ---------------- combine (global max) + attentions + head + lens + x update ----
// grid 64 x 256
__global__ void k_comb(const int* __restrict__ slen, float* __restrict__ ws,
                       float* __restrict__ out, int p, int ts) {
    const int b = blockIdx.x, tid = threadIdx.x;
    const int hs_out = 576 + (p ? 0 : 512);
    __shared__ float red[256];
    __shared__ float feat[1024];
    __shared__ float sc_sh[16];
    __shared__ float lg_s[64];
    float mx = -INFINITY;
#pragma unroll
    for (int i = 0; i < 4; ++i) mx = fmaxf(mx, ws[OFF_MD + (tid + 256 * i) * 2]);
    red[tid] = mx;
    __syncthreads();
    for (int s = 128; s > 0; s >>= 1) {
        if (tid < s) red[tid] = fmaxf(red[tid], red[tid + s]);
        __syncthreads();
    }
    float m_g = red[0];
    __syncthreads();
    if (tid < 16) {
        float mi = ws[OFF_MD + (b * 16 + tid) * 2];
        float Di = ws[OFF_MD + (b * 16 + tid) * 2 + 1];
        float s = __expf(mi - m_g);
        sc_sh[tid] = s;
        red[tid] = s * Di;
    }
    __syncthreads();
    float dn = 0.0f;
#pragma unroll
    for (int j = 0; j < 16; ++j) dn += red[j];
    float inv = 1.0f / (dn + 1e-5f);
    float cx = 0.0f, cy = 0.0f;
#pragma unroll 4
    for (int i = 0; i < 16; ++i) {
        float s = sc_sh[i];
        float2 v = *(const float2*)&ws[OFF_CP + (size_t)(b * 16 + i) * 512 + tid * 2];
        cx += s * v.x;
        cy += s * v.y;
    }
    cx *= inv; cy *= inv;
    feat[512 + tid * 2] = cx;
    feat[512 + tid * 2 + 1] = cy;
    ws[OFF_XT + (size_t)(64 + tid * 2) * 64 + b] = cx;
    ws[OFF_XT + (size_t)(64 + tid * 2 + 1) * 64 + b] = cy;
    feat[tid * 2]     = ws[OFF_XT + (size_t)(hs_out + tid * 2) * 64 + b];
    feat[tid * 2 + 1] = ws[OFF_XT + (size_t)(hs_out + tid * 2 + 1) * 64 + b];
    int L = slen[b];
#pragma unroll
    for (int q = 0; q < 4; ++q) {
        int t = tid + 256 * q;
        float e = ws[OFF_E + (size_t)b * 1024 + t];
        float a = (t < L) ? __expf(e - m_g) * inv : 0.0f;
        out[OUT_ATT + (size_t)b * 131072 + (size_t)ts * 1024 + t] = a;
    }
    __syncthreads();
    int v = tid >> 2, qq = tid & 3;
    const float4* w4 = (const float4*)(ws + OFF_W2 + (size_t)v * 1024 + qq * 256);
    const float4* f4 = (const float4*)feat + qq * 64;
    float acc = 0.0f;
#pragma unroll 8
    for (int k = 0; k < 64; ++k) acc += dot4(w4[k], f4[k]);
    acc += __shfl_xor(acc, 1);
    acc += __shfl_xor(acc, 2);
    if (qq == 0) lg_s[v] = acc;
    __syncthreads();
    if (tid < 64) {
        float lg = lg_s[tid] + ws[OFF_B2 + tid];
        float mxv = lg;
#pragma unroll
        for (int mm = 1; mm < 64; mm <<= 1) mxv = fmaxf(mxv, __shfl_xor(mxv, mm));
        float ev = __expf(lg - mxv);
        float s = ev;
#pragma unroll
        for (int mm = 1; mm < 64; mm <<= 1) s += __shfl_xor(s, mm);
        float y = ev / s;
        out[OUT_YH + (size_t)b * 8192 + ts * 64 + tid] = y;
        ws[OFF_XT + (size_t)tid * 64 + b] = y;
        float av = lg;
        int ai = tid;
#pragma unroll
        for (int mm = 1; mm < 64; mm <<= 1) {
            float ov = __shfl_xor(av, mm);
            int oi = __shfl_xor(ai, mm);
            if (ov > av || (ov == av && oi < ai)) { av = ov; ai = oi; }
        }
        if (tid == 0) {
            int* lens = (int*)ws + OFF_LENS;
            if (ai == 1 && lens[b] > ts) lens[b] = ts + 1;   // EOS == 1
        }
    }
}

__global__ void k_lens(const float* __restrict__ ws, float* __restrict__ out) {
    int tid = threadIdx.x;   // 64
    out[OUT_LENS + tid] = (float)(((const int*)ws)[OFF_LENS + tid]);
}

extern "C" void kernel_launch(void* const* d_in, const int* in_sizes, int n_in,
                              void* d_out, int out_size, void* d_ws, size_t ws_size,
                              hipStream_t stream) {
    (void)in_sizes; (void)n_in; (void)out_size;
    const float* h    = (const float*)d_in[0];
    const float* Wih  = (const float*)d_in[1];
    const float* Whh  = (const float*)d_in[2];
    const float* bih  = (const float*)d_in[3];
    const float* bhh  = (const float*)d_in[4];
    const float* fc1w = (const float*)d_in[5];
    const float* fc1b = (const float*)d_in[6];
    const float* fc2w = (const float*)d_in[7];
    const int*   slen = (const int*)d_in[8];
    float* ws  = (float*)d_ws;
    float* out = (float*)d_out;
    const bool use16 = (ws_size >= WS_NEED);

    k_init<<<528, 256, 0, stream>>>(h, ws);
    k_fuse<<<256, 256, 0, stream>>>(fc1w, fc1b, fc2w, ws);
    if (use16) k_hconv<<<16384, 256, 0, stream>>>(h, ws);
    for (int t = 0; t < 128; t++) {
        int p = t & 1;
        k_gates<<<256, 512, 0, stream>>>(Wih, Whh, bih, bhh, ws, p);
        if (use16) k_attn16<<<1024, 256, 0, stream>>>(slen, ws, p);
        else       k_attn<<<1024, 256, 0, stream>>>(h, slen, ws, p);
        k_comb<<<64, 256, 0, stream>>>(slen, ws, out, p, t);
    }
    k_lens<<<1, 64, 0, stream>>>(ws, out);
}